// Round 6
// baseline (216.182 us; speedup 1.0000x reference)
//
#include <hip/hip_runtime.h>
#include <hip/hip_bf16.h>

typedef unsigned short u16;
typedef __attribute__((ext_vector_type(8))) short short8;   // 8 bf16 (4 VGPRs)
typedef __attribute__((ext_vector_type(4))) float f32x4;

#define NN 9
#define DX 128
#define KP 64
#define LL 32
#define NALL 100000
#define BMAX 8192
#define NBM 16   // b's per k_main block (16 waves of 1024-thread block)
#define NBP 64   // proto blocks in k_lin, 1 prototype per block

#define MFMA(a, b, c) __builtin_amdgcn_mfma_f32_16x16x32_bf16(a, b, c, 0, 0, 0)

// ---------- cross-kernel tables ----------
__device__ __align__(16) float g_tns[LL * NN];        // normalized theta_s [l][j]
__device__ __align__(16) float g_hprn[KP];            // ||h_proto_root||^2 [k]
__device__ __align__(16) float g_hpt[32 * KP];        // hp^T [j][k]
__device__ __align__(16) float g_rpst[NN * KP];       // sorted proto_rad [m][k]
__device__ __align__(16) u16   g_hroot[BMAX * DX];    // root LN'd h rows, bf16
__device__ __align__(16) u16   g_hpool[BMAX * DX];    // pooled neighbor h, bf16
__device__ __align__(16) float g_hrn[BMAX];           // ||h_root||^2 per b
__device__ __align__(16) u16   g_Cf[BMAX * 576];      // feature sort frags [wgt|-2wv] per b
__device__ __align__(16) u16   g_Cs[BMAX * 576];      // structural sort frags per b
__device__ __align__(16) float g_drad[BMAX * 64];     // radial distance per (b,k)
__device__ __align__(16) float g_t1x[BMAX];           // t1 feature
__device__ __align__(16) float g_t1s[BMAX];           // t1 structural
// MFMA fragment-packed B tables (bf16)
__device__ __align__(16) u16   g_pW[16384];           // x_lin_w: K=128, N=128
__device__ __align__(16) u16   g_pBt[4096];           // tnx:  K=128, N=32
__device__ __align__(16) u16   g_pBr[8192];           // hprt: K=128, N=64
__device__ __align__(16) u16   g_pBx[36864];          // sw feat [pf^2|pf]: K=576, N=64
__device__ __align__(16) u16   g_pBs[36864];          // sw str  [qf^2|qf]: K=576, N=64
__device__ __align__(16) u16   g_pAn[4096];           // an_w1: K=128, N=32
__device__ __align__(16) u16   g_pWn[4096];           // wn_w1[:128]: K=128, N=32

__device__ __forceinline__ float bf2f(u16 u) {
    union { unsigned u; float f; } v; v.u = ((unsigned)u) << 16; return v.f;
}
__device__ __forceinline__ u16 f2bf(float f) {
    __hip_bfloat16 h = __float2bfloat16(f);
    union { __hip_bfloat16 h; u16 u; } v; v.h = h; return v.u;
}
__device__ __forceinline__ float ldv(const void* p, long i, int f32) {
    return f32 ? ((const float*)p)[i] : bf2f(((const u16*)p)[i]);
}
__device__ __forceinline__ float sigmoidf(float x) { return 1.f / (1.f + expf(-x)); }

__device__ __forceinline__ int bfrag_idx(int ksteps, int ncol, int kd) {
    int ntile = ncol >> 4, n = ncol & 15;
    int kstep = kd >> 5, quad = (kd >> 3) & 3, j = kd & 7;
    return ((ntile * ksteps + kstep) * 64 + quad * 16 + n) * 8 + j;
}

__device__ __forceinline__ void rank9(const float* v, int* r) {
#pragma unroll
    for (int m = 0; m < 9; m++) {
        int rk = 0;
#pragma unroll
        for (int n = 0; n < 9; n++)
            rk += (v[n] < v[m]) || (v[n] == v[m] && n < m);
        r[m] = rk;
    }
}

// ---------------- kernel 0: one-time packing ----------------
__global__ __launch_bounds__(256) void k_pack(
    const void* xlw, const void* theta_x, const void* theta_s,
    const void* an_w1, const void* wn_w1, const void* proto_rad, const void* xlg) {
    int t = threadIdx.x;
    const int f32 = (((const u16*)xlg)[0] == 0);
    if (blockIdx.x == 0) {
        for (int i = t; i < 16384; i += 256) {
            int c = i >> 7, d = i & 127;
            g_pW[bfrag_idx(4, d, c)] = f2bf(ldv(xlw, i, f32));
        }
    } else if (blockIdx.x == 1) {
        if (t < 32) {
            float s = 0;
            for (int d = 0; d < 128; d++) { float v = ldv(theta_x, t * 128 + d, f32); s = fmaf(v, v, s); }
            float inv = 1.f / sqrtf(s);
            for (int d = 0; d < 128; d++)
                g_pBt[bfrag_idx(4, t, d)] = f2bf(ldv(theta_x, t * 128 + d, f32) * inv);
        } else if (t < 64) {
            int l = t - 32;
            float s = 0;
            for (int j = 0; j < 9; j++) { float v = ldv(theta_s, l * 9 + j, f32); s = fmaf(v, v, s); }
            float inv = 1.f / sqrtf(s);
            for (int j = 0; j < 9; j++) g_tns[l * 9 + j] = ldv(theta_s, l * 9 + j, f32) * inv;
        } else if (t < 128) {
            int k = t - 64;
            float v[9]; int r[9];
#pragma unroll
            for (int m = 0; m < 9; m++) v[m] = ldv(proto_rad, k * 9 + m, f32);
            rank9(v, r);
#pragma unroll
            for (int m = 0; m < 9; m++) g_rpst[r[m] * 64 + k] = v[m];
        }
    } else {
        for (int i = t; i < 4096; i += 256) {
            int d = i >> 5, j = i & 31;
            g_pAn[bfrag_idx(4, j, d)] = f2bf(ldv(an_w1, i, f32));
            g_pWn[bfrag_idx(4, j, d)] = f2bf(ldv(wn_w1, i, f32));
        }
    }
}

// ---------------- kernel 1: lin+LN + full per-b precompute; proto blocks run proto chain ----
// Batch blocks (6 b's each): lin+LN -> hS (LDS); then root/pool/hrn, feature pb->Cf,
// BFS + structural chain -> Cs/drad/t1s. All outputs to compact global tables.
__global__ __launch_bounds__(256, 4) void k_lin(
    const void* adj, const void* feat, const int* idxs,
    const void* proto_root, const void* proto_neigh,
    const void* xlb, const void* xlg, const void* xlbt,
    const void* slg, const void* slb, const void* wn_w1,
    const void* proto_dn, int B) {
    __shared__ __align__(16) u16   WfL[16384];   // 32KB W frags; aliased after sync2 (see offsets)
    __shared__ __align__(16) u16   hXpb[1280];   // [10][128] bf16 (proto only)
    __shared__ __align__(16) float pbX[288];     // [9][32] (proto only)
    __shared__ __align__(16) float Cm[84];       // [81] (proto only)
    __shared__ __align__(16) float hsnP[84];     // [81] (proto only)
    // batch-block aliases inside WfL (valid after sync2/sync3):
    u16*      hS    = WfL;                                  // [60][128] 15360 B
    float*    dfL   = (float*)((char*)WfL + 15360);         // [6][100]
    float*    stL   = (float*)((char*)WfL + 17760);         // [6][81]
    float*    pbU   = (float*)((char*)WfL + 19712);         // [6][288] shared feat/struct proj
    float*    rbssL = (float*)((char*)WfL + 26624);         // [6][9]
    float*    wradL = (float*)((char*)WfL + 26840);         // [6][9]
    unsigned* gmL   = (unsigned*)((char*)WfL + 27056);      // [6]
    float*    invL  = (float*)((char*)WfL + 27080);         // [6]

    int t = threadIdx.x, lane = t & 63, w = t >> 6;
    const int f32 = (((const u16*)xlg)[0] == 0);
    int fm = lane & 15, quad = lane >> 4;
    bool isProto = (blockIdx.x < (unsigned)NBP);
    int rcap = isProto ? 10 : 60;
    int base = isProto ? blockIdx.x * 10 : (blockIdx.x - NBP) * 60;
    int rowT = isProto ? KP * 10 : B * 10;
    int bbase = base / 10;

    // ---- stage pre-packed W -> LDS ----
    {
        const short8* src = (const short8*)g_pW;
        short8* dst = (short8*)WfL;
#pragma unroll
        for (int i = 0; i < 8; i++) dst[t + 256 * i] = src[t + 256 * i];
    }

    // ---- gather setup + issue A loads + preload params ----
    int lr = w * 16 + fm, gr = base + lr;
    bool azero = true;
    const void* abuf = feat; long aoff = 0;
    if (lr < rcap && gr < rowT) {
        if (!isProto) {
            int id = idxs[gr];
            if (id != NALL) { azero = false; aoff = (long)id * 128; }
        } else {
            int rr = gr % 10; azero = false;
            if (rr < 9) { abuf = proto_neigh; aoff = (long)((gr / 10) * 9 + rr) * 128; }
            else        { abuf = proto_root;  aoff = (long)(gr / 10) * 128; }
        }
    }
    short8 af[4];
#pragma unroll
    for (int ks = 0; ks < 4; ks++) af[ks] = (short8){0, 0, 0, 0, 0, 0, 0, 0};
    if (!azero) {
        if (f32) {
#pragma unroll
            for (int ks = 0; ks < 4; ks++) {
                const f32x4* src = (const f32x4*)((const float*)abuf + aoff + ks * 32 + quad * 8);
                f32x4 v0 = src[0], v1 = src[1];
                u16* ap = (u16*)&af[ks];
#pragma unroll
                for (int j = 0; j < 4; j++) { ap[j] = f2bf(v0[j]); ap[4 + j] = f2bf(v1[j]); }
            }
        } else {
#pragma unroll
            for (int ks = 0; ks < 4; ks++)
                af[ks] = *(const short8*)((const u16*)abuf + aoff + ks * 32 + quad * 8);
        }
    }
    float bias8[8], gg8[8], bb8[8];
#pragma unroll
    for (int nt = 0; nt < 8; nt++) {
        int col = nt * 16 + fm;
        bias8[nt] = ldv(xlb, col, f32);
        gg8[nt]   = ldv(xlg, col, f32);
        bb8[nt]   = ldv(xlbt, col, f32);
    }
    __syncthreads();   // sync1: WfL ready

    f32x4 acc[8];
#pragma unroll
    for (int nt = 0; nt < 8; nt++) acc[nt] = (f32x4){0.f, 0.f, 0.f, 0.f};
    if (w * 16 < rcap) {
#pragma unroll
        for (int ks = 0; ks < 4; ks++) {
#pragma unroll
            for (int nt = 0; nt < 8; nt++) {
                short8 bf = *(const short8*)(WfL + ((nt * 4 + ks) * 64 + lane) * 8);
                acc[nt] = MFMA(af[ks], bf, acc[nt]);
            }
        }
    }
    __syncthreads();   // sync2: WfL reads done -> safe to alias

    if (w * 16 < rcap) {
#pragma unroll
        for (int reg = 0; reg < 4; reg++) {
            float s = 0, q = 0;
#pragma unroll
            for (int nt = 0; nt < 8; nt++) {
                float v = acc[nt][reg] + bias8[nt];
                s += v; q = fmaf(v, v, q);
            }
#pragma unroll
            for (int m = 1; m < 16; m <<= 1) { s += __shfl_xor(s, m); q += __shfl_xor(q, m); }
            float mu = s * (1.f / 128.f);
            float var = fmaxf(q * (1.f / 128.f) - mu * mu, 0.f);
            float rs = rsqrtf(var + 1e-5f);
            int rowD = w * 16 + quad * 4 + reg, grD = base + rowD;
            if (rowD < rcap && grD < rowT) {
#pragma unroll
                for (int nt = 0; nt < 8; nt++) {
                    float val = (acc[nt][reg] + bias8[nt] - mu) * rs * gg8[nt] + bb8[nt];
                    if (!isProto) hS[rowD * 128 + nt * 16 + fm] = f2bf(val);
                    else          hXpb[rowD * 128 + nt * 16 + fm] = f2bf(val);
                }
            }
        }
    }
    __syncthreads();   // sync3: hS / hXpb ready

    if (!isProto) {
        int nrows = rowT - base; if (nrows > 60) nrows = 60;
        int nb = nrows / 10;

        // ---- BFS (waves 0-1, 16-lane groups, 4 b's per wave) ----
        if (w < 2) {
            int g2 = lane >> 4, b = w * 4 + g2, j = lane & 15, srcb = lane & 48;
            bool bact = (b < nb);
            int bg = bbase + b;
            bool vj = false;
            if (bact && j < 10) vj = (j == 0) || (idxs[bg * 10 + j] != NALL);
            unsigned long long bal = __ballot(vj);
            unsigned gm = (unsigned)(bal >> srcb) & 0x3FFu;
            float invb = 1.f / ((float)__popc(gm & 0x3FEu) + 1e-9f);
            unsigned rowbits = 0;
            if (bact && j < 10) {
                for (int jj = 0; jj < 10; jj++)
                    if (ldv(adj, (long)bg * 100 + j * 10 + jj, f32) > 1e-5f) rowbits |= 1u << jj;
            }
            int dl[10];
#pragma unroll
            for (int jj = 0; jj < 10; jj++) dl[jj] = (jj == j) ? 0 : (((rowbits >> jj) & 1) ? 1 : 10);
            unsigned reach = (j < 10) ? (rowbits | (1u << j)) : 0u;
            for (int s = 2; s <= 9; s++) {
                unsigned nr = reach;
#pragma unroll
                for (int jj = 0; jj < 10; jj++) {
                    unsigned rj = (unsigned)__shfl((int)rowbits, srcb + jj);
                    if ((reach >> jj) & 1) nr |= rj;
                }
                unsigned add = nr & ~reach;
#pragma unroll
                for (int jj = 0; jj < 10; jj++) if ((add >> jj) & 1) dl[jj] = s;
                reach = nr;
                if (__all(add == 0)) break;
            }
            if (bact && j < 10) {
                int mi = (int)((gm >> j) & 1);
#pragma unroll
                for (int jj = 0; jj < 10; jj++) {
                    int mj = (int)((gm >> jj) & 1);
                    dfL[b * 100 + j * 10 + jj] = (mi && mj) ? (float)dl[jj] * 0.1f : 1.0f;
                }
            }
            {   // row-0 distances rank (9 lanes of group)
                float v[9];
#pragma unroll
                for (int m = 0; m < 9; m++) {
                    int dv = __shfl(dl[1 + m], srcb);
                    v[m] = ((gm >> (1 + m)) & 1) ? (float)dv * 0.1f : 1.0f;
                }
                if (bact && j < 9) {
                    float mine = v[0];
#pragma unroll
                    for (int m = 1; m < 9; m++) if (j == m) mine = v[m];
                    int rk = 0;
#pragma unroll
                    for (int n = 0; n < 9; n++) rk += (v[n] < mine) || (v[n] == mine && n < j);
                    rbssL[b * 9 + rk] = mine;
                    wradL[b * 9 + rk] = (((gm >> (1 + j)) & 1) ? 1.f : 0.f) * invb;
                }
                if (bact && j == 0) { gmL[b] = gm; invL[b] = invb; }
            }
        }

        // ---- root row copy + pool/hrn (reads hS) ----
        if (t < 96) {
            int b = t >> 4, i = t & 15;
            if (b < nb)
                ((short8*)(g_hroot + (long)(bbase + b) * 128))[i] = ((const short8*)(hS + b * 10 * 128))[i];
        }
        if (t < 192) {
            int b = t >> 5, l = t & 31;
            int bg = bbase + b;
            if (b < nb) {
                unsigned msk9 = 0; int cnt = 0;
#pragma unroll
                for (int m = 0; m < 9; m++) {
                    if (idxs[bg * 10 + 1 + m] != NALL) { msk9 |= 1u << m; cnt++; }
                }
                float invb = 1.f / ((float)cnt + 1e-9f);
                float rq = 0;
                u16 o[4];
#pragma unroll
                for (int cc = 0; cc < 4; cc++) {
                    int c = l * 4 + cc;
                    float a = 0;
#pragma unroll
                    for (int m = 0; m < 9; m++)
                        if ((msk9 >> m) & 1) a += bf2f(hS[(b * 10 + 1 + m) * 128 + c]);
                    o[cc] = f2bf(a * invb);
                    float rv = bf2f(hS[(b * 10) * 128 + c]);
                    rq = fmaf(rv, rv, rq);
                }
                unsigned* gp = (unsigned*)(g_hpool + (long)bg * 128);
                gp[l * 2]     = (unsigned)o[0] | ((unsigned)o[1] << 16);
                gp[l * 2 + 1] = (unsigned)o[2] | ((unsigned)o[3] << 16);
#pragma unroll
                for (int m = 16; m >= 1; m >>= 1) rq += __shfl_xor(rq, m);
                if (l == 0) g_hrn[bg] = rq;
            }
        }

        // ---- feature projections MFMA: all neighbor rows vs theta_x -> pbU ----
        {
            f32x4 acc0 = {0.f, 0.f, 0.f, 0.f}, acc1 = {0.f, 0.f, 0.f, 0.f};
            int row = w * 16 + fm;
            bool act = (row < nrows) && (row % 10 != 0);
            const u16* arow = hS + row * 128;
#pragma unroll
            for (int ks = 0; ks < 4; ks++) {
                short8 afn = {0, 0, 0, 0, 0, 0, 0, 0};
                if (act) afn = *(const short8*)(arow + ks * 32 + quad * 8);
                short8 b0 = *(const short8*)(g_pBt + ((0 * 4 + ks) * 64 + lane) * 8);
                short8 b1 = *(const short8*)(g_pBt + ((1 * 4 + ks) * 64 + lane) * 8);
                acc0 = MFMA(afn, b0, acc0);
                acc1 = MFMA(afn, b1, acc1);
            }
#pragma unroll
            for (int reg = 0; reg < 4; reg++) {
                int rowD = w * 16 + quad * 4 + reg;
                if (rowD < nrows && (rowD % 10) != 0) {
                    int b = rowD / 10, m = rowD % 10 - 1;
                    pbU[b * 288 + m * 32 + fm]      = acc0[reg];
                    pbU[b * 288 + m * 32 + 16 + fm] = acc1[reg];
                }
            }
        }
        __syncthreads();   // S4: pbU(feat) + dfL + gm ready

        // ---- Cf rank -> g_Cf + t1x ----
        if (t < 192) {
            int b = t >> 5, l = t & 31;
            if (b < nb) {
                int bg = bbase + b;
                unsigned gm = gmL[b]; float invb = invL[b];
                float v[9]; int r[9];
#pragma unroll
                for (int m = 0; m < 9; m++) v[m] = pbU[b * 288 + m * 32 + l];
                rank9(v, r);
                float t1 = 0;
#pragma unroll
                for (int m = 0; m < 9; m++) {
                    float wgt = (((gm >> (1 + m)) & 1) ? 1.f : 0.f) * invb;
                    int slot = l * 9 + r[m];
                    g_Cf[(long)bg * 576 + slot]       = f2bf(wgt);
                    g_Cf[(long)bg * 576 + 288 + slot] = f2bf(-2.f * wgt * v[m]);
                    t1 = fmaf(wgt * v[m], v[m], t1);
                }
#pragma unroll
                for (int m = 16; m >= 1; m >>= 1) t1 += __shfl_xor(t1, m);
                if (l == 0) g_t1x[bg] = t1;
            }
        }
        // ---- hst column sort -> stL ----
        if (t < 54) {
            int b = t / 9, col = t - b * 9;
            if (b < nb) {
                float v[9]; int r[9];
#pragma unroll
                for (int i = 0; i < 9; i++) v[i] = dfL[b * 100 + (1 + i) * 10 + 1 + col];
                rank9(v, r);
#pragma unroll
                for (int i = 0; i < 9; i++) stL[b * 81 + r[i] * 9 + col] = v[i];
            }
        }
        __syncthreads();   // S5: stL ready

        // ---- LN rows of stL in place ----
        if (t < 54) {
            int b = t / 9, row = t - b * 9;
            if (b < nb) {
                float vv[9];
#pragma unroll
                for (int j = 0; j < 9; j++) vv[j] = stL[b * 81 + row * 9 + j];
                float mu = 0;
#pragma unroll
                for (int j = 0; j < 9; j++) mu += vv[j];
                mu *= (1.f / 9.f);
                float var = 0;
#pragma unroll
                for (int j = 0; j < 9; j++) { float d0 = vv[j] - mu; var = fmaf(d0, d0, var); }
                var *= (1.f / 9.f);
                float rs = rsqrtf(var + 1e-5f);
#pragma unroll
                for (int j = 0; j < 9; j++)
                    stL[b * 81 + row * 9 + j] = (vv[j] - mu) * rs * ldv(slg, j, f32) + ldv(slb, j, f32);
            }
        }
        __syncthreads();   // S6: LN done (pbU feat reads finished 2 barriers ago)

        // ---- structural projections -> pbU (overwrite) ----
        if (t < 192) {
            int b = t >> 5, l = t & 31;
            if (b < nb) {
#pragma unroll
                for (int m = 0; m < 9; m++) {
                    float a = 0;
#pragma unroll
                    for (int j = 0; j < 9; j++) a = fmaf(stL[b * 81 + m * 9 + j], g_tns[l * 9 + j], a);
                    pbU[b * 288 + m * 32 + l] = a;
                }
            }
        }
        __syncthreads();   // S7: pbU(struct) ready

        // ---- Cs rank -> g_Cs + t1s ----
        if (t < 192) {
            int b = t >> 5, l = t & 31;
            if (b < nb) {
                int bg = bbase + b;
                unsigned gm = gmL[b]; float invb = invL[b];
                float v[9]; int r[9];
#pragma unroll
                for (int m = 0; m < 9; m++) v[m] = pbU[b * 288 + m * 32 + l];
                rank9(v, r);
                float t1 = 0;
#pragma unroll
                for (int m = 0; m < 9; m++) {
                    float wgt = (((gm >> (1 + m)) & 1) ? 1.f : 0.f) * invb;
                    int slot = l * 9 + r[m];
                    g_Cs[(long)bg * 576 + slot]       = f2bf(wgt);
                    g_Cs[(long)bg * 576 + 288 + slot] = f2bf(-2.f * wgt * v[m]);
                    t1 = fmaf(wgt * v[m], v[m], t1);
                }
#pragma unroll
                for (int m = 16; m >= 1; m >>= 1) t1 += __shfl_xor(t1, m);
                if (l == 0) g_t1s[bg] = t1;
            }
        }
        // ---- drad -> g_drad ----
        for (int i = t; i < nb * 64; i += 256) {
            int b = i >> 6, k = i & 63;
            float a = 0;
#pragma unroll
            for (int m = 0; m < 9; m++) {
                float d0 = rbssL[b * 9 + m] - g_rpst[m * 64 + k];
                a = fmaf(d0 * d0, wradL[b * 9 + m], a);
            }
            g_drad[(long)(bbase + b) * 64 + k] = a;
        }
        return;
    }

    // ================= proto chain (1 prototype per block) =================
    int kb = blockIdx.x;

    for (int i = t; i < 128; i += 256)
        g_pBr[bfrag_idx(4, kb, i)] = hXpb[1152 + i];
    if (w == 0) {
        float v0 = bf2f(hXpb[1152 + lane]);
        float v1 = bf2f(hXpb[1216 + lane]);
        float q = v0 * v0 + v1 * v1;
#pragma unroll
        for (int m = 32; m >= 1; m >>= 1) q += __shfl_xor(q, m);
        if (lane == 0) g_hprn[kb] = q;
    }
    {   // hpt: 256 threads = 32 j's x 8 segments of 16 d's, shuffle-reduce
        int j = t >> 3, sub = t & 7;
        float a = 0;
#pragma unroll
        for (int dd = 0; dd < 16; dd++) {
            int d = sub * 16 + dd;
            a = fmaf(bf2f(hXpb[1152 + d]), ldv(wn_w1, (128 + d) * 32 + j, f32), a);
        }
        a += __shfl_xor(a, 1);
        a += __shfl_xor(a, 2);
        a += __shfl_xor(a, 4);
        if (sub == 0) g_hpt[j * 64 + kb] = a;
    }
    if (w == 0) {
        f32x4 acc0 = {0.f, 0.f, 0.f, 0.f}, acc1 = {0.f, 0.f, 0.f, 0.f};
        const u16* arow2 = hXpb + fm * 128;
#pragma unroll
        for (int ks = 0; ks < 4; ks++) {
            short8 afp = {0, 0, 0, 0, 0, 0, 0, 0};
            if (fm < 9) afp = *(const short8*)(arow2 + ks * 32 + quad * 8);
            short8 b0 = *(const short8*)(g_pBt + ((0 * 4 + ks) * 64 + lane) * 8);
            short8 b1 = *(const short8*)(g_pBt + ((1 * 4 + ks) * 64 + lane) * 8);
            acc0 = MFMA(afp, b0, acc0);
            acc1 = MFMA(afp, b1, acc1);
        }
#pragma unroll
        for (int reg = 0; reg < 4; reg++) {
            int row = quad * 4 + reg;
            if (row < 9) {
                pbX[row * 32 + fm]      = acc0[reg];
                pbX[row * 32 + 16 + fm] = acc1[reg];
            }
        }
    }
    for (int i = t; i < 81; i += 256) {
        int ii = i / 9, jj = i % 9; float v = 0.f;
        if (ii != jj) {
            int a = (ii < jj) ? ii : jj, b2 = (ii < jj) ? jj : ii;
            int p = a * 8 - a * (a - 1) / 2 + (b2 - a - 1);
            v = sigmoidf(ldv(proto_dn, p * 64 + kb, f32));
        }
        Cm[i] = v;
    }
    __syncthreads();
    if (t < 32) {
        float v[9]; int r[9];
#pragma unroll
        for (int m = 0; m < 9; m++) v[m] = pbX[m * 32 + t];
        rank9(v, r);
#pragma unroll
        for (int m = 0; m < 9; m++) {
            int kd = t * 9 + r[m];
            g_pBx[bfrag_idx(18, kb, kd)]       = f2bf(v[m] * v[m]);
            g_pBx[bfrag_idx(18, kb, 288 + kd)] = f2bf(v[m]);
        }
    }
    if (t >= 64 && t < 73) {
        int col = t - 64;
        float v[9]; int r[9];
#pragma unroll
        for (int j = 0; j < 9; j++) v[j] = Cm[j * 9 + col];
        rank9(v, r);
#pragma unroll
        for (int j = 0; j < 9; j++) Cm[r[j] * 9 + col] = v[j];
    }
    __syncthreads();
    if (t < 9) {
        float mu = 0;
#pragma unroll
        for (int j = 0; j < 9; j++) mu += Cm[t * 9 + j];
        mu *= (1.f / 9.f);
        float var = 0;
#pragma unroll
        for (int j = 0; j < 9; j++) { float d0 = Cm[t * 9 + j] - mu; var = fmaf(d0, d0, var); }
        var *= (1.f / 9.f);
        float rs = rsqrtf(var + 1e-5f);
#pragma unroll
        for (int j = 0; j < 9; j++)
            hsnP[t * 9 + j] = (Cm[t * 9 + j] - mu) * rs * ldv(slg, j, f32) + ldv(slb, j, f32);
    }
    __syncthreads();
    if (t < 32) {
#pragma unroll
        for (int m = 0; m < 9; m++) {
            float a = 0;
#pragma unroll
            for (int j = 0; j < 9; j++) a = fmaf(hsnP[m * 9 + j], g_tns[t * 9 + j], a);
            pbX[m * 32 + t] = a;
        }
    }
    __syncthreads();
    if (t < 32) {
        float v[9]; int r[9];
#pragma unroll
        for (int m = 0; m < 9; m++) v[m] = pbX[m * 32 + t];
        rank9(v, r);
#pragma unroll
        for (int m = 0; m < 9; m++) {
            int kd = t * 9 + r[m];
            g_pBs[bfrag_idx(18, kb, kd)]       = f2bf(v[m] * v[m]);
            g_pBs[bfrag_idx(18, kb, 288 + kd)] = f2bf(v[m]);
        }
    }
}

// ---------------- kernel 2: pure P5 — stage per-b tables, MFMA, epilogue ----------------
struct M3 {
    u16   Cf[NBM][584];     // 16B-aligned stride (1168 B)
    u16   Cs[NBM][584];
    u16   hrootL[NBM][136];
    u16   hpoolb[NBM][136];
    float drad[NBM][65];
    float hbv[NBM][33];
    float sc[NBM][9];       // 1:hrn 2:alpha 3:t1x 4:t1s
};
__global__ __launch_bounds__(1024, 8) void k_main(
    const void* an_b1, const void* an_w2, const void* an_b2,
    const void* wn_b1, const void* wn_w2, const void* wn_b2,
    const void* alpha_raw, const void* w_raw, const void* log_gamma,
    const void* xlg, void* out, int B) {
    __shared__ __align__(16) M3 S;
    int t = threadIdx.x, lane = t & 63, w = t >> 6;
    const int f32 = (((const u16*)xlg)[0] == 0);
    int fm = lane & 15, quad = lane >> 4;
    int bw = blockIdx.x * NBM + w;
    bool bv = (bw < B);

    // ================= P0: coalesced stage of per-b tables =================
    if (bv) {
        {
            const short8* src = (const short8*)(g_Cf + (long)bw * 576);
            short8* dst = (short8*)S.Cf[w];
            for (int i = lane; i < 72; i += 64) dst[i] = src[i];
        }
        {
            const short8* src = (const short8*)(g_Cs + (long)bw * 576);
            short8* dst = (short8*)S.Cs[w];
            for (int i = lane; i < 72; i += 64) dst[i] = src[i];
        }
        if (lane < 16) {
            ((short8*)S.hrootL[w])[lane] = ((const short8*)(g_hroot + (long)bw * 128))[lane];
            ((short8*)S.hpoolb[w])[lane] = ((const short8*)(g_hpool + (long)bw * 128))[lane];
        }
        S.drad[w][lane] = g_drad[(long)bw * 64 + lane];
        if (lane == 0) {
            S.sc[w][1] = g_hrn[bw];
            S.sc[w][3] = g_t1x[bw];
            S.sc[w][4] = g_t1s[bw];
        }
    } else {
        short8 z = {0, 0, 0, 0, 0, 0, 0, 0};
        for (int i = lane; i < 72; i += 64) {
            ((short8*)S.Cf[w])[i] = z;
            ((short8*)S.Cs[w])[i] = z;
        }
        if (lane < 16) {
            ((short8*)S.hrootL[w])[lane] = z;
            ((short8*)S.hpoolb[w])[lane] = z;
        }
    }
    __syncthreads();   // SY1

    // ================= P5a: MFMA phase, wave-specialized =================
    f32x4 rd = {0.f, 0.f, 0.f, 0.f};
    f32x4 accF = {0.f, 0.f, 0.f, 0.f}, accS = {0.f, 0.f, 0.f, 0.f};
    if (w < 4) {
#pragma unroll
        for (int ks = 0; ks < 4; ks++) {
            short8 af = *(const short8*)(S.hrootL[fm] + ks * 32 + quad * 8);
            short8 bfr = *(const short8*)(g_pBr + ((w * 4 + ks) * 64 + lane) * 8);
            rd = MFMA(af, bfr, rd);
        }
#pragma unroll
        for (int ks = 0; ks < 18; ks++) {
            short8 aF = *(const short8*)(S.Cf[fm] + ks * 32 + quad * 8);
            short8 aS = *(const short8*)(S.Cs[fm] + ks * 32 + quad * 8);
            short8 bF = *(const short8*)(g_pBx + ((w * 18 + ks) * 64 + lane) * 8);
            short8 bS = *(const short8*)(g_pBs + ((w * 18 + ks) * 64 + lane) * 8);
            accF = MFMA(aF, bF, accF);
            accS = MFMA(aS, bS, accS);
        }
    } else if (w == 4) {
        // hb = hroot @ wn_w1[:128] + b1  -> S.hbv[b][j]
        f32x4 a0 = {0.f, 0.f, 0.f, 0.f}, a1 = {0.f, 0.f, 0.f, 0.f};
#pragma unroll
        for (int ks = 0; ks < 4; ks++) {
            short8 af = *(const short8*)(S.hrootL[fm] + ks * 32 + quad * 8);
            short8 b0 = *(const short8*)(g_pWn + ((0 * 4 + ks) * 64 + lane) * 8);
            short8 b1 = *(const short8*)(g_pWn + ((1 * 4 + ks) * 64 + lane) * 8);
            a0 = MFMA(af, b0, a0);
            a1 = MFMA(af, b1, a1);
        }
        float wb0 = ldv(wn_b1, fm, f32), wb1 = ldv(wn_b1, 16 + fm, f32);
#pragma unroll
        for (int reg = 0; reg < 4; reg++) {
            int b = quad * 4 + reg;
            S.hbv[b][fm]      = a0[reg] + wb0;
            S.hbv[b][16 + fm] = a1[reg] + wb1;
        }
    } else if (w == 5) {
        // alpha = sigmoid(araw + relu(hpool @ an_w1 + b1) @ an_w2 + b2) -> S.sc[b][2]
        f32x4 a0 = {0.f, 0.f, 0.f, 0.f}, a1 = {0.f, 0.f, 0.f, 0.f};
#pragma unroll
        for (int ks = 0; ks < 4; ks++) {
            short8 af = *(const short8*)(S.hpoolb[fm] + ks * 32 + quad * 8);
            short8 b0 = *(const short8*)(g_pAn + ((0 * 4 + ks) * 64 + lane) * 8);
            short8 b1 = *(const short8*)(g_pAn + ((1 * 4 + ks) * 64 + lane) * 8);
            a0 = MFMA(af, b0, a0);
            a1 = MFMA(af, b1, a1);
        }
        float ab0 = ldv(an_b1, fm, f32), ab1 = ldv(an_b1, 16 + fm, f32);
        float aw0 = ldv(an_w2, fm, f32), aw1 = ldv(an_w2, 16 + fm, f32);
        float araw = ldv(alpha_raw, 0, f32), ab2 = ldv(an_b2, 0, f32);
#pragma unroll
        for (int reg = 0; reg < 4; reg++) {
            float s = fmaxf(a0[reg] + ab0, 0.f) * aw0 + fmaxf(a1[reg] + ab1, 0.f) * aw1;
            s += __shfl_xor(s, 1); s += __shfl_xor(s, 2);
            s += __shfl_xor(s, 4); s += __shfl_xor(s, 8);
            if (fm == 0) S.sc[quad * 4 + reg][2] = sigmoidf(araw + s + ab2);
        }
    }
    __syncthreads();   // SY2: hbv + alpha ready

    // ================= P5b: epilogue (waves 0-3; lane owns (b=quad*4+reg, k=w*16+fm)) ====
    if (w < 4) {
        int k = w * 16 + fm;
        float wb2 = ldv(wn_b2, 0, f32);
        float wr  = ldv(w_raw, 0, f32);
        float gamma = expf(ldv(log_gamma, 0, f32));
        float hprnk = g_hprn[k];
        float wl[4] = {0.f, 0.f, 0.f, 0.f};
#pragma unroll 4
        for (int j = 0; j < 32; j++) {
            float hptv = g_hpt[j * 64 + k];
            float w2v = ldv(wn_w2, j, f32);
#pragma unroll
            for (int reg = 0; reg < 4; reg++)
                wl[reg] = fmaf(fmaxf(S.hbv[quad * 4 + reg][j] + hptv, 0.f), w2v, wl[reg]);
        }
#pragma unroll
        for (int reg = 0; reg < 4; reg++) {
            int b = quad * 4 + reg, bb = blockIdx.x * NBM + b;
            if (bb >= B) continue;
            float swf = (S.sc[b][3] + accF[reg]) * (1.f / 32.f);
            float sws = (S.sc[b][4] + accS[reg]) * (1.f / 32.f);
            float drfk = S.sc[b][1] + hprnk - 2.f * rd[reg];
            float wgt = sigmoidf(wr + wl[reg] + wb2);
            float dfeat = wgt * drfk + (1.f - wgt) * swf;
            float dstr  = wgt * S.drad[b][k] + (1.f - wgt) * sws;
            float al = S.sc[b][2];
            float dfgw = al * dfeat + (1.f - al) * dstr;
            if (!(dfgw == dfgw)) dfgw = 1e30f;
            float res = expf(-gamma * dfgw);
            if (f32) ((float*)out)[(long)bb * 64 + k] = res;
            else     ((u16*)out)[(long)bb * 64 + k] = f2bf(res);
        }
    }
}

extern "C" void kernel_launch(void* const* d_in, const int* in_sizes, int n_in,
                              void* d_out, int out_size, void* d_ws, size_t ws_size,
                              hipStream_t stream) {
    const void* adj  = d_in[0];
    const void* feat = d_in[1];
    const int*  idxs = (const int*)d_in[2];
    const void* xlw  = d_in[3];
    const void* xlb  = d_in[4];
    const void* xlg  = d_in[5];
    const void* xlbt = d_in[6];
    const void* slg  = d_in[7];
    const void* slb  = d_in[8];
    const void* thx  = d_in[9];
    const void* ths  = d_in[10];
    const void* araw = d_in[11];
    const void* anw1 = d_in[12];
    const void* anb1 = d_in[13];
    const void* anw2 = d_in[14];
    const void* anb2 = d_in[15];
    const void* wnw1 = d_in[16];
    const void* wnb1 = d_in[17];
    const void* wnw2 = d_in[18];
    const void* wnb2 = d_in[19];
    const void* wraw = d_in[20];
    const void* prt  = d_in[21];
    const void* prn  = d_in[22];
    const void* prad = d_in[23];
    const void* pdn  = d_in[24];
    const void* lgam = d_in[25];
    int B = in_sizes[2] / 10;
    int NBQ = (B * 10 + 59) / 60;

    k_pack<<<3, 256, 0, stream>>>(xlw, thx, ths, anw1, wnw1, prad, xlg);
    k_lin<<<NBP + NBQ, 256, 0, stream>>>(adj, feat, idxs, prt, prn,
                                         xlb, xlg, xlbt, slg, slb, wnw1,
                                         pdn, B);
    k_main<<<(B + NBM - 1) / NBM, 1024, 0, stream>>>(
                                  anb1, anw2, anb2, wnb1, wnw2, wnb2,
                                  araw, wraw, lgam, xlg, d_out, B);
}

// Round 7
// 214.960 us; speedup vs baseline: 1.0057x; 1.0057x over previous
//
#include <hip/hip_runtime.h>
#include <hip/hip_bf16.h>

typedef unsigned short u16;
typedef __attribute__((ext_vector_type(8))) short short8;   // 8 bf16 (4 VGPRs)
typedef __attribute__((ext_vector_type(4))) float f32x4;

#define NN 9
#define DX 128
#define KP 64
#define LL 32
#define NALL 100000
#define BMAX 8192
#define NBM 16   // b's per k_main block (16 waves of 1024-thread block)
#define NBP 64   // proto blocks in k_lin, 1 prototype per block
#define HXR 136  // padded hS row stride (u16) -> bank-rotating for row-stride reads
#define WSTR 4736 // per-wave LDS region stride (bytes)

#define MFMA(a, b, c) __builtin_amdgcn_mfma_f32_16x16x32_bf16(a, b, c, 0, 0, 0)
#define WFENCE() __threadfence_block()

// ---------- cross-kernel tables ----------
__device__ __align__(16) float g_tns[LL * NN];        // normalized theta_s [l][j]
__device__ __align__(16) float g_hprn[KP];            // ||h_proto_root||^2 [k]
__device__ __align__(16) float g_hpt[32 * KP];        // hp^T [j][k]
__device__ __align__(16) float g_rpst[NN * KP];       // sorted proto_rad [m][k]
__device__ __align__(16) u16   g_hroot[BMAX * DX];    // root LN'd h rows, bf16
__device__ __align__(16) u16   g_hpool[BMAX * DX];    // pooled neighbor h, bf16
__device__ __align__(16) float g_hrn[BMAX];           // ||h_root||^2 per b
__device__ __align__(16) u16   g_Cf[BMAX * 576];      // feature sort frags [wgt|-2wv] per b
__device__ __align__(16) u16   g_Cs[BMAX * 576];      // structural sort frags per b
__device__ __align__(16) float g_drad[BMAX * 64];     // radial distance per (b,k)
__device__ __align__(16) float g_t1x[BMAX];           // t1 feature
__device__ __align__(16) float g_t1s[BMAX];           // t1 structural
// MFMA fragment-packed B tables (bf16)
__device__ __align__(16) u16   g_pW[16384];           // x_lin_w: K=128, N=128 (L1-resident)
__device__ __align__(16) u16   g_pBt[4096];           // tnx:  K=128, N=32
__device__ __align__(16) u16   g_pBr[8192];           // hprt: K=128, N=64
__device__ __align__(16) u16   g_pBx[36864];          // sw feat [pf^2|pf]: K=576, N=64
__device__ __align__(16) u16   g_pBs[36864];          // sw str  [qf^2|qf]: K=576, N=64
__device__ __align__(16) u16   g_pAn[4096];           // an_w1: K=128, N=32
__device__ __align__(16) u16   g_pWn[4096];           // wn_w1[:128]: K=128, N=32

__device__ __forceinline__ float bf2f(u16 u) {
    union { unsigned u; float f; } v; v.u = ((unsigned)u) << 16; return v.f;
}
__device__ __forceinline__ u16 f2bf(float f) {
    __hip_bfloat16 h = __float2bfloat16(f);
    union { __hip_bfloat16 h; u16 u; } v; v.h = h; return v.u;
}
__device__ __forceinline__ float ldv(const void* p, long i, int f32) {
    return f32 ? ((const float*)p)[i] : bf2f(((const u16*)p)[i]);
}
__device__ __forceinline__ float sigmoidf(float x) { return 1.f / (1.f + expf(-x)); }

__device__ __forceinline__ int bfrag_idx(int ksteps, int ncol, int kd) {
    int ntile = ncol >> 4, n = ncol & 15;
    int kstep = kd >> 5, quad = (kd >> 3) & 3, j = kd & 7;
    return ((ntile * ksteps + kstep) * 64 + quad * 16 + n) * 8 + j;
}

__device__ __forceinline__ void rank9(const float* v, int* r) {
#pragma unroll
    for (int m = 0; m < 9; m++) {
        int rk = 0;
#pragma unroll
        for (int n = 0; n < 9; n++)
            rk += (v[n] < v[m]) || (v[n] == v[m] && n < m);
        r[m] = rk;
    }
}

// ---------------- kernel 0: one-time packing ----------------
__global__ __launch_bounds__(256) void k_pack(
    const void* xlw, const void* theta_x, const void* theta_s,
    const void* an_w1, const void* wn_w1, const void* proto_rad, const void* xlg) {
    int t = threadIdx.x;
    const int f32 = (((const u16*)xlg)[0] == 0);
    if (blockIdx.x == 0) {
        for (int i = t; i < 16384; i += 256) {
            int c = i >> 7, d = i & 127;
            g_pW[bfrag_idx(4, d, c)] = f2bf(ldv(xlw, i, f32));
        }
    } else if (blockIdx.x == 1) {
        if (t < 32) {
            float s = 0;
            for (int d = 0; d < 128; d++) { float v = ldv(theta_x, t * 128 + d, f32); s = fmaf(v, v, s); }
            float inv = 1.f / sqrtf(s);
            for (int d = 0; d < 128; d++)
                g_pBt[bfrag_idx(4, t, d)] = f2bf(ldv(theta_x, t * 128 + d, f32) * inv);
        } else if (t < 64) {
            int l = t - 32;
            float s = 0;
            for (int j = 0; j < 9; j++) { float v = ldv(theta_s, l * 9 + j, f32); s = fmaf(v, v, s); }
            float inv = 1.f / sqrtf(s);
            for (int j = 0; j < 9; j++) g_tns[l * 9 + j] = ldv(theta_s, l * 9 + j, f32) * inv;
        } else if (t < 128) {
            int k = t - 64;
            float v[9]; int r[9];
#pragma unroll
            for (int m = 0; m < 9; m++) v[m] = ldv(proto_rad, k * 9 + m, f32);
            rank9(v, r);
#pragma unroll
            for (int m = 0; m < 9; m++) g_rpst[r[m] * 64 + k] = v[m];
        }
    } else {
        for (int i = t; i < 4096; i += 256) {
            int d = i >> 5, j = i & 31;
            g_pAn[bfrag_idx(4, j, d)] = f2bf(ldv(an_w1, i, f32));
            g_pWn[bfrag_idx(4, j, d)] = f2bf(ldv(wn_w1, i, f32));
        }
    }
}

// ---------------- kernel 1: wave-autonomous per-b pipeline; proto blocks run proto chain ----
// Batch path: 1 wave = 1 b, zero block barriers. B-frags (g_pW/g_pBt) read from global
// (identical addresses across waves -> L1-resident). Proto path: block-cooperative as before.
__global__ __launch_bounds__(256, 5) void k_lin(
    const void* adj, const void* feat, const int* idxs,
    const void* proto_root, const void* proto_neigh,
    const void* xlb, const void* xlg, const void* xlbt,
    const void* slg, const void* slb, const void* wn_w1,
    const void* proto_dn, int B) {
    __shared__ __align__(16) char sm[4 * WSTR];

    int t = threadIdx.x, lane = t & 63, w = t >> 6;
    const int f32 = (((const u16*)xlg)[0] == 0);
    int fm = lane & 15, quad = lane >> 4;
    bool isProto = (blockIdx.x < (unsigned)NBP);

    if (!isProto) {
        // ---- per-wave LDS region ----
        u16*   hSw = (u16*)(sm + w * WSTR);              // [10][HXR]
        float* pbw = (float*)(sm + w * WSTR + 2720);     // [9][32]
        float* dfw = (float*)(sm + w * WSTR + 3872);     // [10][10]
        float* stw = (float*)(sm + w * WSTR + 4272);     // [81]
        float* rbw = (float*)(sm + w * WSTR + 4608);     // [9]
        float* wrw = (float*)(sm + w * WSTR + 4644);     // [9]

        int bw = (blockIdx.x - NBP) * 4 + w;
        if (bw >= B) return;   // safe: no barriers in this path

        // ---- masks ----
        bool valid = false;
        if (lane < 10) {
            int id = idxs[bw * 10 + lane];
            valid = (lane == 0) || (id != NALL);
        }
        unsigned long long mb = __ballot(valid);
        float inv = 1.f / ((float)__popcll(mb & 0x3FEull) + 1e-9f);

        // ---- issue feature gather for this b's 10 rows ----
        bool azero = true; long aoff = 0;
        if (fm < 10) {
            int id2 = idxs[bw * 10 + fm];
            if (id2 != NALL) { azero = false; aoff = (long)id2 * 128; }
        }
        short8 af[4];
#pragma unroll
        for (int ks = 0; ks < 4; ks++) af[ks] = (short8){0, 0, 0, 0, 0, 0, 0, 0};
        if (!azero) {
            if (f32) {
#pragma unroll
                for (int ks = 0; ks < 4; ks++) {
                    const f32x4* src = (const f32x4*)((const float*)feat + aoff + ks * 32 + quad * 8);
                    f32x4 v0 = src[0], v1 = src[1];
                    u16* ap = (u16*)&af[ks];
#pragma unroll
                    for (int j = 0; j < 4; j++) { ap[j] = f2bf(v0[j]); ap[4 + j] = f2bf(v1[j]); }
                }
            } else {
#pragma unroll
                for (int ks = 0; ks < 4; ks++)
                    af[ks] = *(const short8*)((const u16*)feat + aoff + ks * 32 + quad * 8);
            }
        }

        // ---- BFS (hides gather latency; adj-only) ----
        unsigned rowbits = 0;
        if (lane < 10) {
            for (int j = 0; j < 10; j++)
                if (ldv(adj, (long)bw * 100 + lane * 10 + j, f32) > 1e-5f) rowbits |= 1u << j;
        }
        int dl[10];
#pragma unroll
        for (int j = 0; j < 10; j++) dl[j] = (j == lane) ? 0 : (((rowbits >> j) & 1) ? 1 : 10);
        unsigned reach = (lane < 10) ? (rowbits | (1u << lane)) : 0u;
        for (int s = 2; s <= 9; s++) {
            unsigned nr = reach;
#pragma unroll
            for (int j = 0; j < 10; j++) {
                unsigned rj = __shfl(rowbits, j);
                if ((reach >> j) & 1) nr |= rj;
            }
            unsigned add = nr & ~reach;
#pragma unroll
            for (int j = 0; j < 10; j++) if ((add >> j) & 1) dl[j] = s;
            reach = nr;
            if (__all(add == 0)) break;
        }
        if (lane < 10) {
            int mi = (int)((mb >> lane) & 1);
#pragma unroll
            for (int j = 0; j < 10; j++) {
                int mj = (int)((mb >> j) & 1);
                dfw[lane * 10 + j] = (mi && mj) ? (float)dl[j] * 0.1f : 1.0f;
            }
        }
        {   // row-0 distances: broadcast then 9-lane rank
            float v[9];
#pragma unroll
            for (int m = 0; m < 9; m++) {
                float vm = ((mb >> (1 + m)) & 1) ? (float)dl[1 + m] * 0.1f : 1.0f;
                v[m] = __shfl(vm, 0);
            }
            if (lane < 9) {
                float mine = v[0];
#pragma unroll
                for (int m = 1; m < 9; m++) if (lane == m) mine = v[m];
                int rk = 0;
#pragma unroll
                for (int n = 0; n < 9; n++) rk += (v[n] < mine) || (v[n] == mine && n < lane);
                rbw[rk] = mine;
                wrw[rk] = (((mb >> (1 + lane)) & 1) ? 1.f : 0.f) * inv;
            }
        }

        // ---- lin-MFMA + LN -> hSw ----
        {
            float bias8[8], gg8[8], bb8[8];
#pragma unroll
            for (int nt = 0; nt < 8; nt++) {
                int col = nt * 16 + fm;
                bias8[nt] = ldv(xlb, col, f32);
                gg8[nt]   = ldv(xlg, col, f32);
                bb8[nt]   = ldv(xlbt, col, f32);
            }
            f32x4 acc[8];
#pragma unroll
            for (int nt = 0; nt < 8; nt++) acc[nt] = (f32x4){0.f, 0.f, 0.f, 0.f};
#pragma unroll
            for (int ks = 0; ks < 4; ks++) {
#pragma unroll
                for (int nt = 0; nt < 8; nt++) {
                    short8 bf = *(const short8*)(g_pW + ((nt * 4 + ks) * 64 + lane) * 8);
                    acc[nt] = MFMA(af[ks], bf, acc[nt]);
                }
            }
#pragma unroll
            for (int reg = 0; reg < 4; reg++) {
                float s = 0, q = 0;
#pragma unroll
                for (int nt = 0; nt < 8; nt++) {
                    float v = acc[nt][reg] + bias8[nt];
                    s += v; q = fmaf(v, v, q);
                }
#pragma unroll
                for (int m = 1; m < 16; m <<= 1) { s += __shfl_xor(s, m); q += __shfl_xor(q, m); }
                float mu = s * (1.f / 128.f);
                float var = fmaxf(q * (1.f / 128.f) - mu * mu, 0.f);
                float rs = rsqrtf(var + 1e-5f);
                int rowD = quad * 4 + reg;
                if (rowD < 10) {
#pragma unroll
                    for (int nt = 0; nt < 8; nt++) {
                        float val = (acc[nt][reg] + bias8[nt] - mu) * rs * gg8[nt] + bb8[nt];
                        hSw[rowD * HXR + nt * 16 + fm] = f2bf(val);
                    }
                }
            }
        }
        WFENCE();   // hSw ready (intra-wave)

        // ---- hroot copy + hrn + pool ----
        if (lane < 16)
            ((short8*)(g_hroot + (long)bw * 128))[lane] = ((const short8*)hSw)[lane];
        {
            float v0 = bf2f(hSw[lane]), v1 = bf2f(hSw[64 + lane]);
            float q = v0 * v0 + v1 * v1;
#pragma unroll
            for (int m = 32; m >= 1; m >>= 1) q += __shfl_xor(q, m);
            if (lane == 0) g_hrn[bw] = q;
        }
        {
            float a0 = 0, a1 = 0;
            int c0 = lane * 2, c1 = lane * 2 + 1;
#pragma unroll
            for (int m = 0; m < 9; m++) {
                float msk = ((mb >> (1 + m)) & 1) ? 1.f : 0.f;
                a0 = fmaf(bf2f(hSw[(1 + m) * HXR + c0]), msk, a0);
                a1 = fmaf(bf2f(hSw[(1 + m) * HXR + c1]), msk, a1);
            }
            unsigned pk = (unsigned)f2bf(a0 * inv) | ((unsigned)f2bf(a1 * inv) << 16);
            ((unsigned*)(g_hpool + (long)bw * 128))[lane] = pk;
        }

        // ---- feature projections MFMA -> pbw ----
        {
            f32x4 acc0 = {0.f, 0.f, 0.f, 0.f}, acc1 = {0.f, 0.f, 0.f, 0.f};
            const u16* arow = hSw + (1 + fm) * HXR;
#pragma unroll
            for (int ks = 0; ks < 4; ks++) {
                short8 afn = {0, 0, 0, 0, 0, 0, 0, 0};
                if (fm < 9) afn = *(const short8*)(arow + ks * 32 + quad * 8);
                short8 b0 = *(const short8*)(g_pBt + ((0 * 4 + ks) * 64 + lane) * 8);
                short8 b1 = *(const short8*)(g_pBt + ((1 * 4 + ks) * 64 + lane) * 8);
                acc0 = MFMA(afn, b0, acc0);
                acc1 = MFMA(afn, b1, acc1);
            }
#pragma unroll
            for (int reg = 0; reg < 4; reg++) {
                int row = quad * 4 + reg;
                if (row < 9) {
                    pbw[row * 32 + fm]      = acc0[reg];
                    pbw[row * 32 + 16 + fm] = acc1[reg];
                }
            }
        }
        WFENCE();

        // ---- Cf rank -> g_Cf + t1x ----
        {
            float t1 = 0;
            if (lane < 32) {
                float v[9]; int r[9];
#pragma unroll
                for (int m = 0; m < 9; m++) v[m] = pbw[m * 32 + lane];
                rank9(v, r);
#pragma unroll
                for (int m = 0; m < 9; m++) {
                    float wgt = (((mb >> (1 + m)) & 1) ? 1.f : 0.f) * inv;
                    int slot = lane * 9 + r[m];
                    g_Cf[(long)bw * 576 + slot]       = f2bf(wgt);
                    g_Cf[(long)bw * 576 + 288 + slot] = f2bf(-2.f * wgt * v[m]);
                    t1 = fmaf(wgt * v[m], v[m], t1);
                }
            }
#pragma unroll
            for (int m = 16; m >= 1; m >>= 1) t1 += __shfl_xor(t1, m);
            if (lane == 0) g_t1x[bw] = t1;
        }
        // ---- hst column sort -> stw ----
        if (lane < 9) {
            float v[9]; int r[9];
#pragma unroll
            for (int i = 0; i < 9; i++) v[i] = dfw[(1 + i) * 10 + 1 + lane];
            rank9(v, r);
#pragma unroll
            for (int i = 0; i < 9; i++) stw[r[i] * 9 + lane] = v[i];
        }
        WFENCE();
        // ---- LN rows of stw in place ----
        if (lane < 9) {
            float vv[9];
#pragma unroll
            for (int j = 0; j < 9; j++) vv[j] = stw[lane * 9 + j];
            float mu = 0;
#pragma unroll
            for (int j = 0; j < 9; j++) mu += vv[j];
            mu *= (1.f / 9.f);
            float var = 0;
#pragma unroll
            for (int j = 0; j < 9; j++) { float d0 = vv[j] - mu; var = fmaf(d0, d0, var); }
            var *= (1.f / 9.f);
            float rs = rsqrtf(var + 1e-5f);
#pragma unroll
            for (int j = 0; j < 9; j++)
                stw[lane * 9 + j] = (vv[j] - mu) * rs * ldv(slg, j, f32) + ldv(slb, j, f32);
        }
        WFENCE();
        // ---- structural projections -> pbw ----
        {
            int l = lane & 31;
            int m0 = (lane < 32) ? 0 : 5, m1 = (lane < 32) ? 5 : 9;
            for (int m = m0; m < m1; m++) {
                float a = 0;
#pragma unroll
                for (int j = 0; j < 9; j++) a = fmaf(stw[m * 9 + j], g_tns[l * 9 + j], a);
                pbw[m * 32 + l] = a;
            }
        }
        WFENCE();
        // ---- Cs rank -> g_Cs + t1s ----
        {
            float t1 = 0;
            if (lane < 32) {
                float v[9]; int r[9];
#pragma unroll
                for (int m = 0; m < 9; m++) v[m] = pbw[m * 32 + lane];
                rank9(v, r);
#pragma unroll
                for (int m = 0; m < 9; m++) {
                    float wgt = (((mb >> (1 + m)) & 1) ? 1.f : 0.f) * inv;
                    int slot = lane * 9 + r[m];
                    g_Cs[(long)bw * 576 + slot]       = f2bf(wgt);
                    g_Cs[(long)bw * 576 + 288 + slot] = f2bf(-2.f * wgt * v[m]);
                    t1 = fmaf(wgt * v[m], v[m], t1);
                }
            }
#pragma unroll
            for (int m = 16; m >= 1; m >>= 1) t1 += __shfl_xor(t1, m);
            if (lane == 0) g_t1s[bw] = t1;
        }
        // ---- drad ----
        {
            float a = 0;
#pragma unroll
            for (int m = 0; m < 9; m++) {
                float d0 = rbw[m] - g_rpst[m * 64 + lane];
                a = fmaf(d0 * d0, wrw[m], a);
            }
            g_drad[(long)bw * 64 + lane] = a;
        }
        return;
    }

    // ================= proto chain (1 prototype per block) =================
    u16*   hXpb = (u16*)sm;              // [10][128]
    float* pbX  = (float*)(sm + 2560);   // [9][32]
    float* Cm   = (float*)(sm + 3712);   // [81]
    float* hsnP = (float*)(sm + 4048);   // [81]
    int kb = blockIdx.x;

    if (w == 0) {   // lin+LN for the 10 proto rows (B-frags from g_pW, L1-hot)
        const void* abuf; long aoff;
        if (fm < 9) { abuf = proto_neigh; aoff = (long)(kb * 9 + fm) * 128; }
        else        { abuf = proto_root;  aoff = (long)kb * 128; }
        bool arow = (fm < 10);
        short8 af[4];
#pragma unroll
        for (int ks = 0; ks < 4; ks++) af[ks] = (short8){0, 0, 0, 0, 0, 0, 0, 0};
        if (arow) {
            if (f32) {
#pragma unroll
                for (int ks = 0; ks < 4; ks++) {
                    const f32x4* src = (const f32x4*)((const float*)abuf + aoff + ks * 32 + quad * 8);
                    f32x4 v0 = src[0], v1 = src[1];
                    u16* ap = (u16*)&af[ks];
#pragma unroll
                    for (int j = 0; j < 4; j++) { ap[j] = f2bf(v0[j]); ap[4 + j] = f2bf(v1[j]); }
                }
            } else {
#pragma unroll
                for (int ks = 0; ks < 4; ks++)
                    af[ks] = *(const short8*)((const u16*)abuf + aoff + ks * 32 + quad * 8);
            }
        }
        float bias8[8], gg8[8], bb8[8];
#pragma unroll
        for (int nt = 0; nt < 8; nt++) {
            int col = nt * 16 + fm;
            bias8[nt] = ldv(xlb, col, f32);
            gg8[nt]   = ldv(xlg, col, f32);
            bb8[nt]   = ldv(xlbt, col, f32);
        }
        f32x4 acc[8];
#pragma unroll
        for (int nt = 0; nt < 8; nt++) acc[nt] = (f32x4){0.f, 0.f, 0.f, 0.f};
#pragma unroll
        for (int ks = 0; ks < 4; ks++) {
#pragma unroll
            for (int nt = 0; nt < 8; nt++) {
                short8 bf = *(const short8*)(g_pW + ((nt * 4 + ks) * 64 + lane) * 8);
                acc[nt] = MFMA(af[ks], bf, acc[nt]);
            }
        }
#pragma unroll
        for (int reg = 0; reg < 4; reg++) {
            float s = 0, q = 0;
#pragma unroll
            for (int nt = 0; nt < 8; nt++) {
                float v = acc[nt][reg] + bias8[nt];
                s += v; q = fmaf(v, v, q);
            }
#pragma unroll
            for (int m = 1; m < 16; m <<= 1) { s += __shfl_xor(s, m); q += __shfl_xor(q, m); }
            float mu = s * (1.f / 128.f);
            float var = fmaxf(q * (1.f / 128.f) - mu * mu, 0.f);
            float rs = rsqrtf(var + 1e-5f);
            int rowD = quad * 4 + reg;
            if (rowD < 10) {
#pragma unroll
                for (int nt = 0; nt < 8; nt++) {
                    float val = (acc[nt][reg] + bias8[nt] - mu) * rs * gg8[nt] + bb8[nt];
                    hXpb[rowD * 128 + nt * 16 + fm] = f2bf(val);
                }
            }
        }
    }
    __syncthreads();   // hXpb ready

    for (int i = t; i < 128; i += 256)
        g_pBr[bfrag_idx(4, kb, i)] = hXpb[1152 + i];
    if (w == 0) {
        float v0 = bf2f(hXpb[1152 + lane]);
        float v1 = bf2f(hXpb[1216 + lane]);
        float q = v0 * v0 + v1 * v1;
#pragma unroll
        for (int m = 32; m >= 1; m >>= 1) q += __shfl_xor(q, m);
        if (lane == 0) g_hprn[kb] = q;
    }
    {   // hpt: 256 threads = 32 j's x 8 segments of 16 d's, shuffle-reduce
        int j = t >> 3, sub = t & 7;
        float a = 0;
#pragma unroll
        for (int dd = 0; dd < 16; dd++) {
            int d = sub * 16 + dd;
            a = fmaf(bf2f(hXpb[1152 + d]), ldv(wn_w1, (128 + d) * 32 + j, f32), a);
        }
        a += __shfl_xor(a, 1);
        a += __shfl_xor(a, 2);
        a += __shfl_xor(a, 4);
        if (sub == 0) g_hpt[j * 64 + kb] = a;
    }
    if (w == 0) {
        f32x4 acc0 = {0.f, 0.f, 0.f, 0.f}, acc1 = {0.f, 0.f, 0.f, 0.f};
        const u16* arow2 = hXpb + fm * 128;
#pragma unroll
        for (int ks = 0; ks < 4; ks++) {
            short8 afp = {0, 0, 0, 0, 0, 0, 0, 0};
            if (fm < 9) afp = *(const short8*)(arow2 + ks * 32 + quad * 8);
            short8 b0 = *(const short8*)(g_pBt + ((0 * 4 + ks) * 64 + lane) * 8);
            short8 b1 = *(const short8*)(g_pBt + ((1 * 4 + ks) * 64 + lane) * 8);
            acc0 = MFMA(afp, b0, acc0);
            acc1 = MFMA(afp, b1, acc1);
        }
#pragma unroll
        for (int reg = 0; reg < 4; reg++) {
            int row = quad * 4 + reg;
            if (row < 9) {
                pbX[row * 32 + fm]      = acc0[reg];
                pbX[row * 32 + 16 + fm] = acc1[reg];
            }
        }
    }
    for (int i = t; i < 81; i += 256) {
        int ii = i / 9, jj = i % 9; float v = 0.f;
        if (ii != jj) {
            int a = (ii < jj) ? ii : jj, b2 = (ii < jj) ? jj : ii;
            int p = a * 8 - a * (a - 1) / 2 + (b2 - a - 1);
            v = sigmoidf(ldv(proto_dn, p * 64 + kb, f32));
        }
        Cm[i] = v;
    }
    __syncthreads();
    if (t < 32) {
        float v[9]; int r[9];
#pragma unroll
        for (int m = 0; m < 9; m++) v[m] = pbX[m * 32 + t];
        rank9(v, r);
#pragma unroll
        for (int m = 0; m < 9; m++) {
            int kd = t * 9 + r[m];
            g_pBx[bfrag_idx(18, kb, kd)]       = f2bf(v[m] * v[m]);
            g_pBx[bfrag_idx(18, kb, 288 + kd)] = f2bf(v[m]);
        }
    }
    if (t >= 64 && t < 73) {
        int col = t - 64;
        float v[9]; int r[9];
#pragma unroll
        for (int j = 0; j < 9; j++) v[j] = Cm[j * 9 + col];
        rank9(v, r);
#pragma unroll
        for (int j = 0; j < 9; j++) Cm[r[j] * 9 + col] = v[j];
    }
    __syncthreads();
    if (t < 9) {
        float mu = 0;
#pragma unroll
        for (int j = 0; j < 9; j++) mu += Cm[t * 9 + j];
        mu *= (1.f / 9.f);
        float var = 0;
#pragma unroll
        for (int j = 0; j < 9; j++) { float d0 = Cm[t * 9 + j] - mu; var = fmaf(d0, d0, var); }
        var *= (1.f / 9.f);
        float rs = rsqrtf(var + 1e-5f);
#pragma unroll
        for (int j = 0; j < 9; j++)
            hsnP[t * 9 + j] = (Cm[t * 9 + j] - mu) * rs * ldv(slg, j, f32) + ldv(slb, j, f32);
    }
    __syncthreads();
    if (t < 32) {
#pragma unroll
        for (int m = 0; m < 9; m++) {
            float a = 0;
#pragma unroll
            for (int j = 0; j < 9; j++) a = fmaf(hsnP[m * 9 + j], g_tns[t * 9 + j], a);
            pbX[m * 32 + t] = a;
        }
    }
    __syncthreads();
    if (t < 32) {
        float v[9]; int r[9];
#pragma unroll
        for (int m = 0; m < 9; m++) v[m] = pbX[m * 32 + t];
        rank9(v, r);
#pragma unroll
        for (int m = 0; m < 9; m++) {
            int kd = t * 9 + r[m];
            g_pBs[bfrag_idx(18, kb, kd)]       = f2bf(v[m] * v[m]);
            g_pBs[bfrag_idx(18, kb, 288 + kd)] = f2bf(v[m]);
        }
    }
}

// ---------------- kernel 2: pure P5 — stage per-b tables, MFMA, epilogue ----------------
struct M3 {
    u16   Cf[NBM][584];     // 16B-aligned stride (1168 B)
    u16   Cs[NBM][584];
    u16   hrootL[NBM][136];
    u16   hpoolb[NBM][136];
    float drad[NBM][65];
    float hbv[NBM][33];
    float sc[NBM][9];       // 1:hrn 2:alpha 3:t1x 4:t1s
};
__global__ __launch_bounds__(1024, 8) void k_main(
    const void* an_b1, const void* an_w2, const void* an_b2,
    const void* wn_b1, const void* wn_w2, const void* wn_b2,
    const void* alpha_raw, const void* w_raw, const void* log_gamma,
    const void* xlg, void* out, int B) {
    __shared__ __align__(16) M3 S;
    int t = threadIdx.x, lane = t & 63, w = t >> 6;
    const int f32 = (((const u16*)xlg)[0] == 0);
    int fm = lane & 15, quad = lane >> 4;
    int bw = blockIdx.x * NBM + w;
    bool bv = (bw < B);

    // ================= P0: coalesced stage of per-b tables =================
    if (bv) {
        {
            const short8* src = (const short8*)(g_Cf + (long)bw * 576);
            short8* dst = (short8*)S.Cf[w];
            for (int i = lane; i < 72; i += 64) dst[i] = src[i];
        }
        {
            const short8* src = (const short8*)(g_Cs + (long)bw * 576);
            short8* dst = (short8*)S.Cs[w];
            for (int i = lane; i < 72; i += 64) dst[i] = src[i];
        }
        if (lane < 16) {
            ((short8*)S.hrootL[w])[lane] = ((const short8*)(g_hroot + (long)bw * 128))[lane];
            ((short8*)S.hpoolb[w])[lane] = ((const short8*)(g_hpool + (long)bw * 128))[lane];
        }
        S.drad[w][lane] = g_drad[(long)bw * 64 + lane];
        if (lane == 0) {
            S.sc[w][1] = g_hrn[bw];
            S.sc[w][3] = g_t1x[bw];
            S.sc[w][4] = g_t1s[bw];
        }
    } else {
        short8 z = {0, 0, 0, 0, 0, 0, 0, 0};
        for (int i = lane; i < 72; i += 64) {
            ((short8*)S.Cf[w])[i] = z;
            ((short8*)S.Cs[w])[i] = z;
        }
        if (lane < 16) {
            ((short8*)S.hrootL[w])[lane] = z;
            ((short8*)S.hpoolb[w])[lane] = z;
        }
    }
    __syncthreads();   // SY1

    // ================= P5a: MFMA phase, wave-specialized =================
    f32x4 rd = {0.f, 0.f, 0.f, 0.f};
    f32x4 accF = {0.f, 0.f, 0.f, 0.f}, accS = {0.f, 0.f, 0.f, 0.f};
    if (w < 4) {
#pragma unroll
        for (int ks = 0; ks < 4; ks++) {
            short8 af = *(const short8*)(S.hrootL[fm] + ks * 32 + quad * 8);
            short8 bfr = *(const short8*)(g_pBr + ((w * 4 + ks) * 64 + lane) * 8);
            rd = MFMA(af, bfr, rd);
        }
#pragma unroll
        for (int ks = 0; ks < 18; ks++) {
            short8 aF = *(const short8*)(S.Cf[fm] + ks * 32 + quad * 8);
            short8 aS = *(const short8*)(S.Cs[fm] + ks * 32 + quad * 8);
            short8 bF = *(const short8*)(g_pBx + ((w * 18 + ks) * 64 + lane) * 8);
            short8 bS = *(const short8*)(g_pBs + ((w * 18 + ks) * 64 + lane) * 8);
            accF = MFMA(aF, bF, accF);
            accS = MFMA(aS, bS, accS);
        }
    } else if (w == 4) {
        f32x4 a0 = {0.f, 0.f, 0.f, 0.f}, a1 = {0.f, 0.f, 0.f, 0.f};
#pragma unroll
        for (int ks = 0; ks < 4; ks++) {
            short8 af = *(const short8*)(S.hrootL[fm] + ks * 32 + quad * 8);
            short8 b0 = *(const short8*)(g_pWn + ((0 * 4 + ks) * 64 + lane) * 8);
            short8 b1 = *(const short8*)(g_pWn + ((1 * 4 + ks) * 64 + lane) * 8);
            a0 = MFMA(af, b0, a0);
            a1 = MFMA(af, b1, a1);
        }
        float wb0 = ldv(wn_b1, fm, f32), wb1 = ldv(wn_b1, 16 + fm, f32);
#pragma unroll
        for (int reg = 0; reg < 4; reg++) {
            int b = quad * 4 + reg;
            S.hbv[b][fm]      = a0[reg] + wb0;
            S.hbv[b][16 + fm] = a1[reg] + wb1;
        }
    } else if (w == 5) {
        f32x4 a0 = {0.f, 0.f, 0.f, 0.f}, a1 = {0.f, 0.f, 0.f, 0.f};
#pragma unroll
        for (int ks = 0; ks < 4; ks++) {
            short8 af = *(const short8*)(S.hpoolb[fm] + ks * 32 + quad * 8);
            short8 b0 = *(const short8*)(g_pAn + ((0 * 4 + ks) * 64 + lane) * 8);
            short8 b1 = *(const short8*)(g_pAn + ((1 * 4 + ks) * 64 + lane) * 8);
            a0 = MFMA(af, b0, a0);
            a1 = MFMA(af, b1, a1);
        }
        float ab0 = ldv(an_b1, fm, f32), ab1 = ldv(an_b1, 16 + fm, f32);
        float aw0 = ldv(an_w2, fm, f32), aw1 = ldv(an_w2, 16 + fm, f32);
        float araw = ldv(alpha_raw, 0, f32), ab2 = ldv(an_b2, 0, f32);
#pragma unroll
        for (int reg = 0; reg < 4; reg++) {
            float s = fmaxf(a0[reg] + ab0, 0.f) * aw0 + fmaxf(a1[reg] + ab1, 0.f) * aw1;
            s += __shfl_xor(s, 1); s += __shfl_xor(s, 2);
            s += __shfl_xor(s, 4); s += __shfl_xor(s, 8);
            if (fm == 0) S.sc[quad * 4 + reg][2] = sigmoidf(araw + s + ab2);
        }
    }
    __syncthreads();   // SY2: hbv + alpha ready

    // ================= P5b: epilogue =================
    if (w < 4) {
        int k = w * 16 + fm;
        float wb2 = ldv(wn_b2, 0, f32);
        float wr  = ldv(w_raw, 0, f32);
        float gamma = expf(ldv(log_gamma, 0, f32));
        float hprnk = g_hprn[k];
        float wl[4] = {0.f, 0.f, 0.f, 0.f};
#pragma unroll 4
        for (int j = 0; j < 32; j++) {
            float hptv = g_hpt[j * 64 + k];
            float w2v = ldv(wn_w2, j, f32);
#pragma unroll
            for (int reg = 0; reg < 4; reg++)
                wl[reg] = fmaf(fmaxf(S.hbv[quad * 4 + reg][j] + hptv, 0.f), w2v, wl[reg]);
        }
#pragma unroll
        for (int reg = 0; reg < 4; reg++) {
            int b = quad * 4 + reg, bb = blockIdx.x * NBM + b;
            if (bb >= B) continue;
            float swf = (S.sc[b][3] + accF[reg]) * (1.f / 32.f);
            float sws = (S.sc[b][4] + accS[reg]) * (1.f / 32.f);
            float drfk = S.sc[b][1] + hprnk - 2.f * rd[reg];
            float wgt = sigmoidf(wr + wl[reg] + wb2);
            float dfeat = wgt * drfk + (1.f - wgt) * swf;
            float dstr  = wgt * S.drad[b][k] + (1.f - wgt) * sws;
            float al = S.sc[b][2];
            float dfgw = al * dfeat + (1.f - al) * dstr;
            if (!(dfgw == dfgw)) dfgw = 1e30f;
            float res = expf(-gamma * dfgw);
            if (f32) ((float*)out)[(long)bb * 64 + k] = res;
            else     ((u16*)out)[(long)bb * 64 + k] = f2bf(res);
        }
    }
}

extern "C" void kernel_launch(void* const* d_in, const int* in_sizes, int n_in,
                              void* d_out, int out_size, void* d_ws, size_t ws_size,
                              hipStream_t stream) {
    const void* adj  = d_in[0];
    const void* feat = d_in[1];
    const int*  idxs = (const int*)d_in[2];
    const void* xlw  = d_in[3];
    const void* xlb  = d_in[4];
    const void* xlg  = d_in[5];
    const void* xlbt = d_in[6];
    const void* slg  = d_in[7];
    const void* slb  = d_in[8];
    const void* thx  = d_in[9];
    const void* ths  = d_in[10];
    const void* araw = d_in[11];
    const void* anw1 = d_in[12];
    const void* anb1 = d_in[13];
    const void* anw2 = d_in[14];
    const void* anb2 = d_in[15];
    const void* wnw1 = d_in[16];
    const void* wnb1 = d_in[17];
    const void* wnw2 = d_in[18];
    const void* wnb2 = d_in[19];
    const void* wraw = d_in[20];
    const void* prt  = d_in[21];
    const void* prn  = d_in[22];
    const void* prad = d_in[23];
    const void* pdn  = d_in[24];
    const void* lgam = d_in[25];
    int B = in_sizes[2] / 10;
    int NBW = (B + 3) / 4;

    k_pack<<<3, 256, 0, stream>>>(xlw, thx, ths, anw1, wnw1, prad, xlg);
    k_lin<<<NBP + NBW, 256, 0, stream>>>(adj, feat, idxs, prt, prn,
                                         xlb, xlg, xlbt, slg, slb, wnw1,
                                         pdn, B);
    k_main<<<(B + NBM - 1) / NBM, 1024, 0, stream>>>(
                                  anb1, anw2, anb2, wnb1, wnw2, wnb2,
                                  araw, wraw, lgam, xlg, d_out, B);
}